// Round 1
// baseline (105454.309 us; speedup 1.0000x reference)
//
#include <hip/hip_runtime.h>

#define BATCH  64
#define TT     512
#define IDIM   64
#define HDIM   512
#define NAHEAD 24
#define NWG    256

__device__ __forceinline__ float4 ld4(const float* p) {
  return *reinterpret_cast<const float4*>(p);
}
__device__ __forceinline__ float sigm(float x) { return 1.0f / (1.0f + expf(-x)); }

// ---------------------------------------------------------------------------
// Persistent LSTM layer: 256 WGs x 512 threads. WG wg owns h-columns
// {2wg, 2wg+1} for the entire sequence. Threads: b = tid&63, ks = tid>>6
// (8-way contraction split). Per thread: 8 dot-products (2 cols x 4 gates).
// h ping-pongs in global memory; flag-array barrier per step.
// ---------------------------------------------------------------------------
__global__ __launch_bounds__(512, 2)
void lstm_layer_kernel(const float* __restrict__ in, long stride_t, long stride_b, int Din,
                       const float* __restrict__ w_ih, const float* __restrict__ w_hh,
                       const float* __restrict__ b_ih, const float* __restrict__ b_hh,
                       float* __restrict__ out_seq,   // [T][B][H]
                       float* __restrict__ h_buf,     // [2][B][H], slot0 zeroed
                       float* __restrict__ hT, float* __restrict__ cT, // [B][H]
                       unsigned* __restrict__ flags)  // [NWG], zeroed
{
  const int tid = threadIdx.x;
  const int wg  = blockIdx.x;
  const int b   = tid & 63;
  const int ks  = tid >> 6;            // 0..7
  const int jj0 = wg * 2;
  const int K   = Din + HDIM;
  const int KS  = K >> 3;              // 72 (L0) or 128 (L1), multiple of 4
  const int k0  = ks * KS;

  __shared__ float part[8][BATCH][8];  // 16 KB
  __shared__ float gl[8][BATCH];       // 2 KB

  // 8 weight-row pointers: d = gate*2 + col, row r = gate*H + jj0 + col
  const float* wih[8];
  const float* whh[8];
#pragma unroll
  for (int d = 0; d < 8; ++d) {
    int r = (d >> 1) * HDIM + jj0 + (d & 1);
    wih[d] = w_ih + (long)r * Din;
    whh[d] = w_hh + (long)r * HDIM;
  }
  // bias for the dot this thread reduces in the reduce phase (d == ks)
  const int rd = (ks >> 1) * HDIM + jj0 + (ks & 1);
  const float mybias = b_ih[rd] + b_hh[rd];

  // split this thread's k-range [k0, k0+KS) at the Din boundary
  const int a0 = (k0 < Din) ? k0 : Din;
  const int a1 = (k0 + KS < Din) ? (k0 + KS) : Din;
  const int c0 = (k0 > Din) ? (k0 - Din) : 0;
  const int c1 = (k0 + KS > Din) ? (k0 + KS - Din) : 0;

  float c_reg = 0.0f;   // cell state, valid for tid < 128 (b, col=tid>>6)

  for (int t = 0; t < TT; ++t) {
    if (t > 0) {
      if (tid < 64) {
        const unsigned tgt = (unsigned)t;
        for (;;) {
          int ok = 1;
#pragma unroll
          for (int i = 0; i < 4; ++i) {
            unsigned f = __hip_atomic_load(&flags[tid * 4 + i], __ATOMIC_RELAXED,
                                           __HIP_MEMORY_SCOPE_AGENT);
            ok &= (f >= tgt);
          }
          if (__all(ok)) break;
          __builtin_amdgcn_s_sleep(2);
        }
      }
      __syncthreads();
      __threadfence();   // acquire: fresh view of h written by other XCDs
    }

    const float* hprev = h_buf + (size_t)(t & 1) * (BATCH * HDIM);
    float*       hnext = h_buf + (size_t)((t + 1) & 1) * (BATCH * HDIM);
    const float* inrow = in + (long)t * stride_t + (long)b * stride_b;
    const float* hrow  = hprev + b * HDIM;

    float acc[8] = {0.f, 0.f, 0.f, 0.f, 0.f, 0.f, 0.f, 0.f};
    for (int k = a0; k < a1; k += 4) {
      float4 v = ld4(inrow + k);
#pragma unroll
      for (int d = 0; d < 8; ++d) {
        float4 w = ld4(wih[d] + k);
        acc[d] += v.x * w.x + v.y * w.y + v.z * w.z + v.w * w.w;
      }
    }
    for (int k = c0; k < c1; k += 4) {
      float4 v = ld4(hrow + k);
#pragma unroll
      for (int d = 0; d < 8; ++d) {
        float4 w = ld4(whh[d] + k);
        acc[d] += v.x * w.x + v.y * w.y + v.z * w.z + v.w * w.w;
      }
    }
#pragma unroll
    for (int d = 0; d < 8; ++d) part[d][b][ks] = acc[d];
    __syncthreads();

    {  // reduce: thread handles dot d == ks for its b
      float s = 0.f;
#pragma unroll
      for (int i = 0; i < 8; ++i) s += part[ks][b][i];
      gl[ks][b] = s + mybias;
    }
    __syncthreads();

    if (tid < 128) {
      const int col = tid >> 6;
      const int jj  = jj0 + col;
      float gi = gl[0 + col][b];
      float gf = gl[2 + col][b];
      float gg = gl[4 + col][b];
      float go = gl[6 + col][b];
      float cn = sigm(gf) * c_reg + sigm(gi) * tanhf(gg);
      float hn = sigm(go) * tanhf(cn);
      c_reg = cn;
      hnext[b * HDIM + jj] = hn;
      out_seq[((long)t * BATCH + b) * HDIM + jj] = hn;
      if (t == TT - 1) { hT[b * HDIM + jj] = hn; cT[b * HDIM + jj] = cn; }
    }
    __threadfence();    // release: make h stores visible device-wide
    __syncthreads();
    if (tid == 0)
      __hip_atomic_store(&flags[wg], (unsigned)(t + 1), __ATOMIC_RELEASE,
                         __HIP_MEMORY_SCOPE_AGENT);
  }
}

// ---------------------------------------------------------------------------
// enc [T][B][H] -> encT [B][H][T] (64x64 tiles, LDS pad 65)
// ---------------------------------------------------------------------------
__global__ __launch_bounds__(256)
void transpose_enc(const float* __restrict__ enc, float* __restrict__ encT)
{
  __shared__ float tile[64][65];
  const int b  = blockIdx.z;
  const int t0 = blockIdx.y * 64;
  const int h0 = blockIdx.x * 64;
  const int lane = threadIdx.x & 63;
  const int w    = threadIdx.x >> 6;   // 0..3
#pragma unroll 4
  for (int i = 0; i < 16; ++i) {
    int row = w + i * 4;  // t offset
    tile[row][lane] = enc[((long)(t0 + row) * BATCH + b) * HDIM + h0 + lane];
  }
  __syncthreads();
#pragma unroll 4
  for (int i = 0; i < 16; ++i) {
    int row = w + i * 4;  // h offset
    encT[((long)b * HDIM + h0 + row) * TT + t0 + lane] = tile[lane][row];
  }
}

// ---------------------------------------------------------------------------
// Persistent attention decoder: 256 WGs x 256 threads, 24 steps,
// 5 flag-barriers per step. h ping-pongs in hbuf (init from hT in-kernel).
// ---------------------------------------------------------------------------
__global__ __launch_bounds__(256, 1)
void decoder_kernel(const float* __restrict__ enc,   // [T][B][H]
                    const float* __restrict__ encT,  // [B][H][T]
                    const float* __restrict__ w_ih, const float* __restrict__ w_hh,
                    const float* __restrict__ b_ih, const float* __restrict__ b_hh,
                    const float* __restrict__ w_fc, const float* __restrict__ b_fc,
                    const float* __restrict__ hT,    // [B][H]
                    const float* __restrict__ cT,    // [B][H]
                    float* __restrict__ hbuf,        // [2][B][H]
                    float* __restrict__ dec_in,      // [B][H], zeroed
                    float* __restrict__ xi,          // [B][H]
                    float* __restrict__ scores,      // [B][T]
                    float* __restrict__ mz,          // [B][2]
                    float* __restrict__ out,         // [B][24][C]
                    unsigned* __restrict__ flags)    // [NWG], zeroed
{
  const int tid = threadIdx.x;
  const int wg  = blockIdx.x;
  const int b   = tid & 63;
  const int q   = tid >> 6;   // 0..3

  __shared__ float part[8][BATCH][4];  // 8 KB
  __shared__ float gl[8][BATCH];       // 2 KB
  __shared__ float red[2][2][BATCH];   // 1 KB
  __shared__ float red2[256];          // 1 KB

  unsigned bar = 0;
  auto barrier = [&]() {
    __threadfence();
    __syncthreads();
    ++bar;
    if (tid == 0)
      __hip_atomic_store(&flags[wg], bar, __ATOMIC_RELEASE, __HIP_MEMORY_SCOPE_AGENT);
    if (tid < 64) {
      for (;;) {
        int ok = 1;
#pragma unroll
        for (int i = 0; i < 4; ++i) {
          unsigned f = __hip_atomic_load(&flags[tid * 4 + i], __ATOMIC_RELAXED,
                                         __HIP_MEMORY_SCOPE_AGENT);
          ok &= (f >= bar);
        }
        if (__all(ok)) break;
        __builtin_amdgcn_s_sleep(2);
      }
    }
    __syncthreads();
    __threadfence();
  };

  // init h slot0 from hT, c from cT (each WG copies its 2 owned columns)
  float c_reg = 0.f;
  if (tid < 128) {
    int jj = wg * 2 + (tid >> 6);
    hbuf[b * HDIM + jj] = hT[b * HDIM + jj];
    c_reg = cT[b * HDIM + jj];
  }
  barrier();

  for (int s = 0; s < NAHEAD; ++s) {
    const float* h_cur = hbuf + (size_t)(s & 1) * (BATCH * HDIM);
    float*       h_nxt = hbuf + (size_t)((s + 1) & 1) * (BATCH * HDIM);

    // ---- P1: scores for t in {2wg, 2wg+1} -------------------------------
    {
      const int tloc = q & 1, khalf = q >> 1;
      const int t = wg * 2 + tloc;
      const float* er = enc + ((long)t * BATCH + b) * HDIM + khalf * 256;
      const float* hr = h_cur + b * HDIM + khalf * 256;
      float a = 0.f;
      for (int k = 0; k < 256; k += 4) {
        float4 e = ld4(er + k), h = ld4(hr + k);
        a += e.x * h.x + e.y * h.y + e.z * h.z + e.w * h.w;
      }
      red[tloc][khalf][b] = a;
    }
    __syncthreads();
    if (tid < 128) {
      int tloc = tid >> 6;
      scores[b * TT + wg * 2 + tloc] = red[tloc][0][b] + red[tloc][1][b];
    }
    barrier();

    // ---- P2: softmax stats (WG w<64 handles batch row w) ----------------
    if (wg < 64) {
      const int bo = wg;
      float v0 = scores[bo * TT + tid];
      float v1 = scores[bo * TT + tid + 256];
      red2[tid] = fmaxf(v0, v1);
      __syncthreads();
      for (int st = 128; st > 0; st >>= 1) {
        if (tid < st) red2[tid] = fmaxf(red2[tid], red2[tid + st]);
        __syncthreads();
      }
      float m = red2[0];
      __syncthreads();
      red2[tid] = expf(v0 - m) + expf(v1 - m);
      __syncthreads();
      for (int st = 128; st > 0; st >>= 1) {
        if (tid < st) red2[tid] += red2[tid + st];
        __syncthreads();
      }
      if (tid == 0) { mz[bo * 2] = m; mz[bo * 2 + 1] = 1.f / red2[0]; }
    }
    barrier();

    // ---- P3: ctx + xi for h-cols {2wg, 2wg+1} ---------------------------
    {
      const int col = q & 1, thalf = q >> 1;
      const int hc = wg * 2 + col;
      const float m = mz[b * 2], rZ = mz[b * 2 + 1];
      const float* sr = scores + b * TT + thalf * 256;
      const float* er = encT + ((long)b * HDIM + hc) * TT + thalf * 256;
      float a = 0.f;
      for (int k = 0; k < 256; k += 4) {
        float4 sc = ld4(sr + k), e = ld4(er + k);
        a += expf(sc.x - m) * e.x + expf(sc.y - m) * e.y +
             expf(sc.z - m) * e.z + expf(sc.w - m) * e.w;
      }
      red[col][thalf][b] = a * rZ;
    }
    __syncthreads();
    if (tid < 128) {
      int col = tid >> 6;
      int hc = wg * 2 + col;
      xi[b * HDIM + hc] = red[col][0][b] + red[col][1][b] + dec_in[b * HDIM + hc];
    }
    barrier();

    // ---- P4: gates (K = 1024 concat of xi ; h), update c/h --------------
    {
      const int jj0 = wg * 2;
      const int ko = (q & 1) * 256;
      const float* xr    = (q < 2) ? (xi + b * HDIM + ko) : (h_cur + b * HDIM + ko);
      const float* wbase = (q < 2) ? w_ih : w_hh;
      const float* wr[8];
#pragma unroll
      for (int d = 0; d < 8; ++d) {
        int r = (d >> 1) * HDIM + jj0 + (d & 1);
        wr[d] = wbase + (long)r * HDIM + ko;
      }
      float acc[8] = {0.f, 0.f, 0.f, 0.f, 0.f, 0.f, 0.f, 0.f};
      for (int k = 0; k < 256; k += 4) {
        float4 v = ld4(xr + k);
#pragma unroll
        for (int d = 0; d < 8; ++d) {
          float4 w = ld4(wr[d] + k);
          acc[d] += v.x * w.x + v.y * w.y + v.z * w.z + v.w * w.w;
        }
      }
#pragma unroll
      for (int d = 0; d < 8; ++d) part[d][b][q] = acc[d];
    }
    __syncthreads();
    {
#pragma unroll
      for (int dd = 0; dd < 2; ++dd) {
        int d = q + dd * 4;
        float ssum = part[d][b][0] + part[d][b][1] + part[d][b][2] + part[d][b][3];
        int r = (d >> 1) * HDIM + wg * 2 + (d & 1);
        gl[d][b] = ssum + b_ih[r] + b_hh[r];
      }
    }
    __syncthreads();
    if (tid < 128) {
      const int col = tid >> 6;
      const int jj = wg * 2 + col;
      float gi = gl[0 + col][b], gf = gl[2 + col][b];
      float gg = gl[4 + col][b], go = gl[6 + col][b];
      float cn = sigm(gf) * c_reg + sigm(gi) * tanhf(gg);
      float hn = sigm(go) * tanhf(cn);
      c_reg = cn;
      h_nxt[b * HDIM + jj] = hn;
    }
    barrier();

    // ---- P5: pred = h @ w_fc^T + b_fc -----------------------------------
    {
      const int col = q & 1, khalf = q >> 1;
      const int cc = wg * 2 + col;
      const float* wrp = w_fc + (long)cc * HDIM + khalf * 256;
      const float* hr  = h_nxt + b * HDIM + khalf * 256;
      float a = 0.f;
      for (int k = 0; k < 256; k += 4) {
        float4 w = ld4(wrp + k), h = ld4(hr + k);
        a += w.x * h.x + w.y * h.y + w.z * h.z + w.w * h.w;
      }
      red[col][khalf][b] = a;
    }
    __syncthreads();
    if (tid < 128) {
      int col = tid >> 6;
      int cc = wg * 2 + col;
      float p = red[col][0][b] + red[col][1][b] + b_fc[cc];
      out[((long)b * NAHEAD + s) * HDIM + cc] = p;
      dec_in[b * HDIM + cc] = p;
    }
    barrier();
  }
}

// ---------------------------------------------------------------------------
extern "C" void kernel_launch(void* const* d_in, const int* in_sizes, int n_in,
                              void* d_out, int out_size, void* d_ws, size_t ws_size,
                              hipStream_t stream) {
  const float* x     = (const float*)d_in[0];
  const float* w_ih0 = (const float*)d_in[1];
  const float* w_hh0 = (const float*)d_in[2];
  const float* b_ih0 = (const float*)d_in[3];
  const float* b_hh0 = (const float*)d_in[4];
  const float* w_ih1 = (const float*)d_in[5];
  const float* w_hh1 = (const float*)d_in[6];
  const float* b_ih1 = (const float*)d_in[7];
  const float* b_hh1 = (const float*)d_in[8];
  const float* w_ihd = (const float*)d_in[9];
  const float* w_hhd = (const float*)d_in[10];
  const float* b_ihd = (const float*)d_in[11];
  const float* b_hhd = (const float*)d_in[12];
  const float* w_fc  = (const float*)d_in[13];
  const float* b_fc  = (const float*)d_in[14];
  float* out = (float*)d_out;

  char* ws = (char*)d_ws;
  size_t off = 0;
  auto alloc = [&](size_t bytes) -> void* {
    void* p = ws + off;
    off += (bytes + 255) & ~(size_t)255;
    return p;
  };

  // ---- zero region (one memset) ----
  unsigned* flags0 = (unsigned*)alloc(NWG * 4);
  unsigned* flags1 = (unsigned*)alloc(NWG * 4);
  unsigned* flagsD = (unsigned*)alloc(NWG * 4);
  float* hbuf0  = (float*)alloc(2 * BATCH * HDIM * 4);
  float* hbuf1  = (float*)alloc(2 * BATCH * HDIM * 4);
  float* dec_in = (float*)alloc(BATCH * HDIM * 4);
  const size_t zero_bytes = off;
  // ---- no-init scratch ----
  float* hT0   = (float*)alloc(BATCH * HDIM * 4);
  float* cT0   = (float*)alloc(BATCH * HDIM * 4);
  float* hT    = (float*)alloc(BATCH * HDIM * 4);
  float* cT    = (float*)alloc(BATCH * HDIM * 4);
  float* hbufD = (float*)alloc(2 * BATCH * HDIM * 4);
  float* xi    = (float*)alloc(BATCH * HDIM * 4);
  float* scores= (float*)alloc(BATCH * TT * 4);
  float* mz    = (float*)alloc(BATCH * 2 * 4);
  float* seq0  = (float*)alloc((size_t)TT * BATCH * HDIM * 4);
  float* enc   = (float*)alloc((size_t)TT * BATCH * HDIM * 4);
  float* encT  = (float*)alloc((size_t)TT * BATCH * HDIM * 4);
  (void)ws_size; (void)in_sizes; (void)n_in; (void)out_size;

  hipMemsetAsync(d_ws, 0, zero_bytes, stream);

  // encoder layer 0: input x [B][T][I]
  lstm_layer_kernel<<<NWG, 512, 0, stream>>>(
      x, (long)IDIM, (long)TT * IDIM, IDIM,
      w_ih0, w_hh0, b_ih0, b_hh0, seq0, hbuf0, hT0, cT0, flags0);

  // encoder layer 1: input seq0 [T][B][H]
  lstm_layer_kernel<<<NWG, 512, 0, stream>>>(
      seq0, (long)BATCH * HDIM, (long)HDIM, HDIM,
      w_ih1, w_hh1, b_ih1, b_hh1, enc, hbuf1, hT, cT, flags1);

  transpose_enc<<<dim3(8, 8, 64), 256, 0, stream>>>(enc, encT);

  decoder_kernel<<<NWG, 256, 0, stream>>>(
      enc, encT, w_ihd, w_hhd, b_ihd, b_hhd, w_fc, b_fc,
      hT, cT, hbufD, dec_in, xi, scores, mz, out, flagsD);
}

// Round 2
// 23694.147 us; speedup vs baseline: 4.4506x; 4.4506x over previous
//
#include <hip/hip_runtime.h>

#define BATCH  64
#define TT     512
#define IDIM   64
#define HDIM   512
#define NAHEAD 24
#define NWG    256

__device__ __forceinline__ float4 ld4(const float* p) {
  return *reinterpret_cast<const float4*>(p);
}
__device__ __forceinline__ float sigm(float x) { return 1.0f / (1.0f + expf(-x)); }

// Relaxed agent-scope access: compiles to global_load/store_dword sc0 sc1
// (bypass L1 + per-XCD L2, coherence point = memory-side L3). No fences.
__device__ __forceinline__ float lda(const float* p) {
  return __hip_atomic_load(p, __ATOMIC_RELAXED, __HIP_MEMORY_SCOPE_AGENT);
}
__device__ __forceinline__ void sta(float* p, float v) {
  __hip_atomic_store(p, v, __ATOMIC_RELAXED, __HIP_MEMORY_SCOPE_AGENT);
}
__device__ __forceinline__ unsigned ldau(const unsigned* p) {
  return __hip_atomic_load(p, __ATOMIC_RELAXED, __HIP_MEMORY_SCOPE_AGENT);
}
__device__ __forceinline__ void stau(unsigned* p, unsigned v) {
  __hip_atomic_store(p, v, __ATOMIC_RELAXED, __HIP_MEMORY_SCOPE_AGENT);
}

// Wave 0 polls all 256 flags >= tgt, then workgroup barrier.
__device__ __forceinline__ void wait_flags(const unsigned* flags, unsigned tgt, int tid) {
  if (tid < 64) {
    for (;;) {
      int ok = 1;
#pragma unroll
      for (int i = 0; i < 4; ++i) {
        unsigned f = ldau(&flags[tid * 4 + i]);
        ok &= (f >= tgt);
      }
      if (__all(ok)) break;
      __builtin_amdgcn_s_sleep(1);
    }
  }
  __syncthreads();
}

// ---------------------------------------------------------------------------
// Persistent LSTM layer: 256 WGs x 512 threads, WG owns h-cols {2wg,2wg+1}.
// All layouts [.][B] so lane=b is coalesced. h via sc-bypass atomics, no fences.
// ---------------------------------------------------------------------------
template <int DIN>
__global__ __launch_bounds__(512, 2)
void lstm_layer(const float* __restrict__ in,   // [T][DIN][B] (cached)
                const float* __restrict__ w_ih, // [4H][DIN]   (cached)
                const float* __restrict__ w_hh, // [4H][H]     (cached)
                const float* __restrict__ b_ih, const float* __restrict__ b_hh,
                float* __restrict__ out_seq,    // [T][H][B]   (cached)
                float* __restrict__ h_buf,      // [2][H][B], slot0 zeroed (sc)
                float* __restrict__ hT, float* __restrict__ cT, // [H][B] (cached)
                unsigned* __restrict__ flags)   // [NWG], zeroed
{
  const int tid = threadIdx.x;
  const int wg  = blockIdx.x;
  const int b   = tid & 63;
  const int ks  = tid >> 6;            // 0..7: contraction split
  const int jj0 = wg * 2;
  constexpr int K  = DIN + HDIM;
  constexpr int KS = K / 8;            // 72 (L0) / 128 (L1), %4 == 0
  const int k0 = ks * KS;

  __shared__ float part[8][BATCH][9];  // stride 9: conflict-free transpose
  __shared__ float gl[8][BATCH];

  const float* wih[8];
  const float* whh[8];
#pragma unroll
  for (int d = 0; d < 8; ++d) {
    int r = (d >> 1) * HDIM + jj0 + (d & 1);   // gate order i,f,g,o
    wih[d] = w_ih + (long)r * DIN;
    whh[d] = w_hh + (long)r * HDIM;
  }
  const int rd = (ks >> 1) * HDIM + jj0 + (ks & 1);
  const float mybias = b_ih[rd] + b_hh[rd];

  // split [k0, k0+KS) at the DIN boundary (input part / h part)
  const int a0 = (k0 < DIN) ? k0 : DIN;
  const int a1 = (k0 + KS < DIN) ? (k0 + KS) : DIN;
  const int c0 = (k0 > DIN) ? (k0 - DIN) : 0;
  const int c1 = (k0 + KS > DIN) ? (k0 + KS - DIN) : 0;

  float c_reg = 0.0f;  // cell state, valid for tid<128 (b, col=tid>>6)

  for (int t = 0; t < TT; ++t) {
    if (t > 0) wait_flags(flags, (unsigned)t, tid);

    const float* hprev = h_buf + (size_t)(t & 1) * (HDIM * BATCH);
    float*       hnext = h_buf + (size_t)((t + 1) & 1) * (HDIM * BATCH);
    const float* in_t  = in + (size_t)t * (DIN * BATCH);

    float acc[8] = {0.f, 0.f, 0.f, 0.f, 0.f, 0.f, 0.f, 0.f};

#pragma unroll 2
    for (int k = a0; k < a1; k += 4) {   // input projection (cached, coalesced)
      float x0 = in_t[(k + 0) * BATCH + b];
      float x1 = in_t[(k + 1) * BATCH + b];
      float x2 = in_t[(k + 2) * BATCH + b];
      float x3 = in_t[(k + 3) * BATCH + b];
#pragma unroll
      for (int d = 0; d < 8; ++d) {
        float4 w = ld4(wih[d] + k);
        acc[d] += x0 * w.x + x1 * w.y + x2 * w.z + x3 * w.w;
      }
    }
#pragma unroll 2
    for (int k = c0; k < c1; k += 4) {   // recurrent part (sc-bypass, coalesced)
      float h0 = lda(hprev + (k + 0) * BATCH + b);
      float h1 = lda(hprev + (k + 1) * BATCH + b);
      float h2 = lda(hprev + (k + 2) * BATCH + b);
      float h3 = lda(hprev + (k + 3) * BATCH + b);
#pragma unroll
      for (int d = 0; d < 8; ++d) {
        float4 w = ld4(whh[d] + k);
        acc[d] += h0 * w.x + h1 * w.y + h2 * w.z + h3 * w.w;
      }
    }

#pragma unroll
    for (int d = 0; d < 8; ++d) part[d][b][ks] = acc[d];
    __syncthreads();

    {  // reduce: thread handles dot d == ks for its b
      float s = 0.f;
#pragma unroll
      for (int i = 0; i < 8; ++i) s += part[ks][b][i];
      gl[ks][b] = s + mybias;
    }
    __syncthreads();

    if (tid < 128) {
      const int col = tid >> 6;
      const int jj  = jj0 + col;
      float gi = gl[0 + col][b];
      float gf = gl[2 + col][b];
      float gg = gl[4 + col][b];
      float go = gl[6 + col][b];
      float cn = sigm(gf) * c_reg + sigm(gi) * tanhf(gg);
      float hn = sigm(go) * tanhf(cn);
      c_reg = cn;
      sta(hnext + jj * BATCH + b, hn);                       // sc store
      out_seq[(size_t)t * (HDIM * BATCH) + jj * BATCH + b] = hn;  // cached
      if (t == TT - 1) { hT[jj * BATCH + b] = hn; cT[jj * BATCH + b] = cn; }
    }
    __syncthreads();   // drains vmcnt(0) per wave before s_barrier -> publish OK
    if (tid == 0) stau(&flags[wg], (unsigned)(t + 1));
  }
}

// ---------------------------------------------------------------------------
// x [B][T*I] -> xT [T*I][B]  (64x64 LDS tiles)
// ---------------------------------------------------------------------------
__global__ __launch_bounds__(256)
void transpose_bx(const float* __restrict__ in, float* __restrict__ out, int ncols)
{
  __shared__ float tile[64][65];
  const int c0   = blockIdx.x * 64;
  const int lane = threadIdx.x & 63;
  const int w    = threadIdx.x >> 6;   // 0..3
#pragma unroll
  for (int i = 0; i < 16; ++i) {
    int r = w * 16 + i;
    tile[r][lane] = in[(long)r * ncols + c0 + lane];
  }
  __syncthreads();
#pragma unroll
  for (int i = 0; i < 16; ++i) {
    int c = w * 16 + i;
    out[(long)(c0 + c) * 64 + lane] = tile[lane][c];
  }
}

// ---------------------------------------------------------------------------
// Persistent attention decoder: 256 WGs x 256 threads, 24 steps, 4 flag
// barriers per step. All cross-WG arrays in [.][B] layout via sc atomics.
// dec_in lives in registers (producer thread == consumer thread).
// ---------------------------------------------------------------------------
__global__ __launch_bounds__(256, 2)
void decoder_kernel(const float* __restrict__ enc,   // [T][H][B] (cached)
                    const float* __restrict__ w_ih, const float* __restrict__ w_hh,
                    const float* __restrict__ b_ih, const float* __restrict__ b_hh,
                    const float* __restrict__ w_fc, const float* __restrict__ b_fc,
                    const float* __restrict__ hT,    // [H][B] (cached)
                    const float* __restrict__ cT,    // [H][B] (cached)
                    float* __restrict__ hbuf,        // [2][H][B] (sc)
                    float* __restrict__ xi,          // [H][B]    (sc)
                    float* __restrict__ scores,      // [T][B]    (sc)
                    float* __restrict__ mz,          // [2][B]    (sc)
                    float* __restrict__ out,         // [B][24][C] (cached)
                    unsigned* __restrict__ flags)    // [NWG], zeroed
{
  const int tid = threadIdx.x;
  const int wg  = blockIdx.x;
  const int b   = tid & 63;
  const int q   = tid >> 6;   // 0..3

  __shared__ float part[8][BATCH][5];  // stride 5: conflict-free
  __shared__ float gl[8][BATCH];
  __shared__ float red[2][2][BATCH];
  __shared__ float red2[256];

  unsigned bar = 0;
  auto barrier = [&]() {
    __syncthreads();           // drain all waves' stores (vmcnt(0) pre-barrier)
    ++bar;
    if (tid == 0) stau(&flags[wg], bar);
    wait_flags(flags, bar, tid);
  };

  float c_reg = 0.f;
  float dec_reg = 0.f;  // dec_in[b][wg*2+col] for tid<128
  if (tid < 128) {
    int jj = wg * 2 + (tid >> 6);
    sta(&hbuf[jj * BATCH + b], hT[jj * BATCH + b]);
    c_reg = cT[jj * BATCH + b];
  }
  barrier();

  for (int s = 0; s < NAHEAD; ++s) {
    const float* h_cur = hbuf + (size_t)(s & 1) * (HDIM * BATCH);
    float*       h_nxt = hbuf + (size_t)((s + 1) & 1) * (HDIM * BATCH);

    // ---- P1: scores[t][b] for t in {2wg, 2wg+1} -------------------------
    {
      const int tloc = q & 1, khalf = q >> 1;
      const int t = wg * 2 + tloc;
      const float* er = enc + (size_t)t * (HDIM * BATCH) + khalf * 256 * BATCH;
      const float* hr = h_cur + khalf * 256 * BATCH;
      float a = 0.f;
      for (int k = 0; k < 256; ++k)
        a += er[k * BATCH + b] * lda(hr + k * BATCH + b);
      red[tloc][khalf][b] = a;
    }
    __syncthreads();
    if (tid < 128) {
      int tloc = tid >> 6;
      sta(&scores[(wg * 2 + tloc) * BATCH + b], red[tloc][0][b] + red[tloc][1][b]);
    }
    barrier();

    // ---- P2: softmax stats (WG w<64 handles batch row w) ----------------
    if (wg < 64) {
      const int bo = wg;
      float v0 = lda(&scores[tid * BATCH + bo]);
      float v1 = lda(&scores[(tid + 256) * BATCH + bo]);
      red2[tid] = fmaxf(v0, v1);
      __syncthreads();
      for (int st = 128; st > 0; st >>= 1) {
        if (tid < st) red2[tid] = fmaxf(red2[tid], red2[tid + st]);
        __syncthreads();
      }
      float m = red2[0];
      __syncthreads();
      red2[tid] = expf(v0 - m) + expf(v1 - m);
      __syncthreads();
      for (int st = 128; st > 0; st >>= 1) {
        if (tid < st) red2[tid] += red2[tid + st];
        __syncthreads();
      }
      if (tid == 0) { sta(&mz[bo], m); sta(&mz[BATCH + bo], 1.f / red2[0]); }
    }
    barrier();

    // ---- P3: ctx + dec_in -> xi for h-cols {2wg, 2wg+1} -----------------
    {
      const int col = q & 1, thalf = q >> 1;
      const int hc = wg * 2 + col;
      const float m = lda(&mz[b]), rZ = lda(&mz[BATCH + b]);
      float a = 0.f;
      for (int k = 0; k < 256; ++k) {
        int t = thalf * 256 + k;
        float p = expf(lda(&scores[t * BATCH + b]) - m);
        a += p * enc[((size_t)t * HDIM + hc) * BATCH + b];
      }
      red[col][thalf][b] = a * rZ;
    }
    __syncthreads();
    if (tid < 128) {
      int col = tid >> 6;
      int hc = wg * 2 + col;
      sta(&xi[hc * BATCH + b], red[col][0][b] + red[col][1][b] + dec_reg);
    }
    barrier();

    // ---- P4: gates (K=1024 concat xi;h), update c/h ---------------------
    {
      const int jj0 = wg * 2;
      const int ko = (q & 1) * 256;
      const float* xr    = (q < 2) ? (xi + ko * BATCH) : (h_cur + ko * BATCH);
      const float* wbase = (q < 2) ? w_ih : w_hh;
      const float* wr[8];
#pragma unroll
      for (int d = 0; d < 8; ++d) {
        int r = (d >> 1) * HDIM + jj0 + (d & 1);
        wr[d] = wbase + (long)r * HDIM + ko;
      }
      float acc[8] = {0.f, 0.f, 0.f, 0.f, 0.f, 0.f, 0.f, 0.f};
      for (int k = 0; k < 256; k += 4) {
        float v0 = lda(xr + (k + 0) * BATCH + b);
        float v1 = lda(xr + (k + 1) * BATCH + b);
        float v2 = lda(xr + (k + 2) * BATCH + b);
        float v3 = lda(xr + (k + 3) * BATCH + b);
#pragma unroll
        for (int d = 0; d < 8; ++d) {
          float4 w = ld4(wr[d] + k);
          acc[d] += v0 * w.x + v1 * w.y + v2 * w.z + v3 * w.w;
        }
      }
#pragma unroll
      for (int d = 0; d < 8; ++d) part[d][b][q] = acc[d];
    }
    __syncthreads();
    {
#pragma unroll
      for (int dd = 0; dd < 2; ++dd) {
        int d = q + dd * 4;
        float ssum = part[d][b][0] + part[d][b][1] + part[d][b][2] + part[d][b][3];
        int r = (d >> 1) * HDIM + wg * 2 + (d & 1);
        gl[d][b] = ssum + b_ih[r] + b_hh[r];
      }
    }
    __syncthreads();
    if (tid < 128) {
      const int col = tid >> 6;
      const int jj = wg * 2 + col;
      float gi = gl[0 + col][b], gf = gl[2 + col][b];
      float gg = gl[4 + col][b], go = gl[6 + col][b];
      float cn = sigm(gf) * c_reg + sigm(gi) * tanhf(gg);
      float hn = sigm(go) * tanhf(cn);
      c_reg = cn;
      sta(&h_nxt[jj * BATCH + b], hn);
    }
    barrier();

    // ---- P5: pred = h @ w_fc^T + b_fc (no trailing barrier needed) ------
    {
      const int col = q & 1, khalf = q >> 1;
      const int cc = wg * 2 + col;
      const float* wrp = w_fc + (long)cc * HDIM + khalf * 256;
      const float* hr  = h_nxt + khalf * 256 * BATCH;
      float a = 0.f;
      for (int k = 0; k < 256; k += 4) {
        float4 w = ld4(wrp + k);
        a += w.x * lda(hr + (k + 0) * BATCH + b) + w.y * lda(hr + (k + 1) * BATCH + b) +
             w.z * lda(hr + (k + 2) * BATCH + b) + w.w * lda(hr + (k + 3) * BATCH + b);
      }
      red[col][khalf][b] = a;
    }
    __syncthreads();
    if (tid < 128) {
      int col = tid >> 6;
      int cc = wg * 2 + col;
      float p = red[col][0][b] + red[col][1][b] + b_fc[cc];
      out[((long)b * NAHEAD + s) * HDIM + cc] = p;
      dec_reg = p;
    }
    __syncthreads();
  }
}

// ---------------------------------------------------------------------------
extern "C" void kernel_launch(void* const* d_in, const int* in_sizes, int n_in,
                              void* d_out, int out_size, void* d_ws, size_t ws_size,
                              hipStream_t stream) {
  const float* x     = (const float*)d_in[0];
  const float* w_ih0 = (const float*)d_in[1];
  const float* w_hh0 = (const float*)d_in[2];
  const float* b_ih0 = (const float*)d_in[3];
  const float* b_hh0 = (const float*)d_in[4];
  const float* w_ih1 = (const float*)d_in[5];
  const float* w_hh1 = (const float*)d_in[6];
  const float* b_ih1 = (const float*)d_in[7];
  const float* b_hh1 = (const float*)d_in[8];
  const float* w_ihd = (const float*)d_in[9];
  const float* w_hhd = (const float*)d_in[10];
  const float* b_ihd = (const float*)d_in[11];
  const float* b_hhd = (const float*)d_in[12];
  const float* w_fc  = (const float*)d_in[13];
  const float* b_fc  = (const float*)d_in[14];
  float* out = (float*)d_out;

  char* ws = (char*)d_ws;
  size_t off = 0;
  auto alloc = [&](size_t bytes) -> void* {
    void* p = ws + off;
    off += (bytes + 255) & ~(size_t)255;
    return p;
  };

  // ---- zero region (one memset) ----
  unsigned* flags0 = (unsigned*)alloc(NWG * 4);
  unsigned* flags1 = (unsigned*)alloc(NWG * 4);
  unsigned* flagsD = (unsigned*)alloc(NWG * 4);
  float* hbuf0 = (float*)alloc(2 * HDIM * BATCH * 4);
  float* hbuf1 = (float*)alloc(2 * HDIM * BATCH * 4);
  const size_t zero_bytes = off;
  // ---- no-init scratch ----
  float* hT0   = (float*)alloc(HDIM * BATCH * 4);
  float* cT0   = (float*)alloc(HDIM * BATCH * 4);
  float* hT    = (float*)alloc(HDIM * BATCH * 4);
  float* cT    = (float*)alloc(HDIM * BATCH * 4);
  float* hbufD = (float*)alloc(2 * HDIM * BATCH * 4);
  float* xi    = (float*)alloc(HDIM * BATCH * 4);
  float* scores= (float*)alloc(TT * BATCH * 4);
  float* mz    = (float*)alloc(2 * BATCH * 4);
  float* xT    = (float*)alloc((size_t)TT * IDIM * BATCH * 4);
  float* seq0  = (float*)alloc((size_t)TT * HDIM * BATCH * 4);
  float* enc   = (float*)alloc((size_t)TT * HDIM * BATCH * 4);
  (void)ws_size; (void)in_sizes; (void)n_in; (void)out_size;

  hipMemsetAsync(d_ws, 0, zero_bytes, stream);

  // x [B][T*I] -> xT [T*I][B]  (== [T][IDIM][B])
  transpose_bx<<<dim3(TT * IDIM / 64), 256, 0, stream>>>(x, xT, TT * IDIM);

  lstm_layer<IDIM><<<NWG, 512, 0, stream>>>(
      xT, w_ih0, w_hh0, b_ih0, b_hh0, seq0, hbuf0, hT0, cT0, flags0);

  lstm_layer<HDIM><<<NWG, 512, 0, stream>>>(
      seq0, w_ih1, w_hh1, b_ih1, b_hh1, enc, hbuf1, hT, cT, flags1);

  decoder_kernel<<<NWG, 256, 0, stream>>>(
      enc, w_ihd, w_hhd, b_ihd, b_hhd, w_fc, b_fc,
      hT, cT, hbufD, xi, scores, mz, out, flagsD);
}